// Round 12
// baseline (1606.878 us; speedup 1.0000x reference)
//
#include <hip/hip_runtime.h>
#include <hip/hip_fp16.h>
#include <math.h>

// Problem constants (match reference)
#define BB 8
#define SS 2048
#define TT 2048
#define ITERS 20
#define NEG_EPS_INV -10.0f     // -1/EPSILON
#define NWAVE 4                // 256 threads/block
#define NCHUNK 4
#define ROWS 32                // 4 chunks x 4 waves x 2 rows
#define NTILE (SS / ROWS)      // 64 tiles
#define NBLK (NTILE * BB)      // 512 blocks = 2/CU on 256 CUs (co-resident)
#define TINYF 1.17549435e-38f

typedef float vfloat4 __attribute__((ext_vector_type(4)));

__device__ __forceinline__ float4 fma4v(float a, float4 x, float4 y) {
    return make_float4(fmaf(a, x.x, y.x), fmaf(a, x.y, y.y),
                       fmaf(a, x.z, y.z), fmaf(a, x.w, y.w));
}
__device__ __forceinline__ float4 max4(float4 a, float4 b) {
    return make_float4(fmaxf(a.x, b.x), fmaxf(a.y, b.y),
                       fmaxf(a.z, b.z), fmaxf(a.w, b.w));
}
__device__ __forceinline__ float hmax4(float4 a) {
    return fmaxf(fmaxf(a.x, a.y), fmaxf(a.z, a.w));
}
__device__ __forceinline__ float hsum4(float4 a) {
    return (a.x + a.y) + (a.z + a.w);
}
__device__ __forceinline__ float4 exp4m(float4 x, float m) {
    return make_float4(__expf(x.x - m), __expf(x.y - m),
                       __expf(x.z - m), __expf(x.w - m));
}
__device__ __forceinline__ uint h2u(__half2 h) {
    union { __half2 h; uint u; } c; c.h = h; return c.u;
}
__device__ __forceinline__ __half2 u2h(uint u) {
    union { __half2 h; uint u; } c; c.u = u; return c.h;
}
__device__ __forceinline__ uint2 pack4(float4 f) {
    uint2 r;
    r.x = h2u(__float22half2_rn(make_float2(f.x, f.y)));
    r.y = h2u(__float22half2_rn(make_float2(f.z, f.w)));
    return r;
}
__device__ __forceinline__ float4 unpack4(uint2 u) {
    float2 a = __half22float2(u2h(u.x));
    float2 b = __half22float2(u2h(u.y));
    return make_float4(a.x, a.y, b.x, b.y);
}
__device__ __forceinline__ void nt_store4(float4 v, float* p) {
    vfloat4 x = {v.x, v.y, v.z, v.w};
    __builtin_nontemporal_store(x, reinterpret_cast<vfloat4*>(p));
}
__device__ __forceinline__ float aload(const float* p) {
    return __hip_atomic_load(p, __ATOMIC_RELAXED, __HIP_MEMORY_SCOPE_AGENT);
}

// Persistent kernel: all 20 Sinkhorn iterations, one launch.
// Cross-block dataflow is ATOMICS-ONLY (S column-sum planes + barrier
// counters) -> no cache flushes needed, unlike cg::grid sync (~35us).
// Block (tile,b) owns 32 rows of cost[b]; c16 rows are written (iter 0) and
// re-read (iters 1+) by the SAME block -> same CU -> caches stay valid.
// v is held per-thread in registers (vv[8] at this thread's 32 columns),
// updated as vv = ln + vv - log(S_prev) after each barrier.
__global__ __launch_bounds__(256, 2) void sinkhorn_persist(
        const float* __restrict__ cost, uint2* __restrict__ c16,
        const float* __restrict__ mu, const float* __restrict__ nu,
        float* __restrict__ log_u, float* __restrict__ vfinal,
        float* __restrict__ S, int* __restrict__ cnt) {
    int t = threadIdx.x;
    int w = t >> 6, l = t & 63;
    int tile = blockIdx.x, b = blockIdx.y;

    __shared__ float4 acc[NWAVE][512];   // wave-private column accumulators (32 KB)

    // this thread's 8 float4 column groups: cols 4*(i*64+l)..+3
    const float4* nu4 = (const float4*)(nu + (size_t)b * TT);
    float4 ln[8], vv[8];
#pragma unroll
    for (int i = 0; i < 8; ++i) {
        float4 nv = nu4[i * 64 + l];
        ln[i] = make_float4(__logf(fmaxf(nv.x, TINYF)), __logf(fmaxf(nv.y, TINYF)),
                            __logf(fmaxf(nv.z, TINYF)), __logf(fmaxf(nv.w, TINYF)));
        vv[i] = make_float4(0.f, 0.f, 0.f, 0.f);
    }

    for (int k = 0; k < ITERS; ++k) {
        if (k > 0) {
            // barrier: wait for all blocks' iter k-1 column sums
            if (t == 0) {
                while (__hip_atomic_load(&cnt[k - 1], __ATOMIC_ACQUIRE,
                                         __HIP_MEMORY_SCOPE_AGENT) < NBLK)
                    __builtin_amdgcn_s_sleep(32);
            }
            __syncthreads();
            // v update at this thread's columns (atomic loads bypass stale caches)
            const float* Sp = S + (size_t)(k - 1) * (BB * TT) + (size_t)b * TT;
#pragma unroll
            for (int i = 0; i < 8; ++i) {
                int col = (i * 64 + l) * 4;
                float s0 = aload(Sp + col + 0);
                float s1 = aload(Sp + col + 1);
                float s2 = aload(Sp + col + 2);
                float s3 = aload(Sp + col + 3);
                vv[i].x = ln[i].x + vv[i].x - __logf(fmaxf(s0, TINYF));
                vv[i].y = ln[i].y + vv[i].y - __logf(fmaxf(s1, TINYF));
                vv[i].z = ln[i].z + vv[i].z - __logf(fmaxf(s2, TINYF));
                vv[i].w = ln[i].w + vv[i].w - __logf(fmaxf(s3, TINYF));
            }
        }

        // zero this wave's accumulator plane (wave-private; prior readers done
        // at the pre-arrive / post-spin __syncthreads)
#pragma unroll
        for (int i = 0; i < 8; ++i) acc[w][i * 64 + l] = make_float4(0.f, 0.f, 0.f, 0.f);

#pragma unroll
        for (int c = 0; c < NCHUNK; ++c) {
            int r0 = tile * ROWS + c * (2 * NWAVE) + w * 2;  // wave's 1st row
            size_t rowbase = (size_t)(b * SS + r0) * TT;

            float4 x0[8], x1[8];
            if (k == 0) {
                const float4* c4 = (const float4*)(cost + rowbase);
                uint2* cw = c16 + rowbase / 4;        // uint2 = 4 halves
#pragma unroll
                for (int i = 0; i < 8; ++i) x0[i] = c4[i * 64 + l];
#pragma unroll
                for (int i = 0; i < 8; ++i) x1[i] = c4[512 + i * 64 + l];
#pragma unroll
                for (int i = 0; i < 8; ++i) {
                    cw[i * 64 + l] = pack4(x0[i]);
                    cw[512 + i * 64 + l] = pack4(x1[i]);
                }
            } else {
                const uint2* cr = (const uint2*)c16 + rowbase / 4;
#pragma unroll
                for (int i = 0; i < 8; ++i) x0[i] = unpack4(cr[i * 64 + l]);
#pragma unroll
                for (int i = 0; i < 8; ++i) x1[i] = unpack4(cr[512 + i * 64 + l]);
            }
#pragma unroll
            for (int i = 0; i < 8; ++i) {
                x0[i] = fma4v(NEG_EPS_INV, x0[i], vv[i]);
                x1[i] = fma4v(NEG_EPS_INV, x1[i], vv[i]);
            }

            // row max (in-wave butterfly)
            float4 a0 = x0[0], a1 = x1[0];
#pragma unroll
            for (int i = 1; i < 8; ++i) { a0 = max4(a0, x0[i]); a1 = max4(a1, x1[i]); }
            float m0 = hmax4(a0), m1 = hmax4(a1);
#pragma unroll
            for (int off = 1; off < 64; off <<= 1) {
                m0 = fmaxf(m0, __shfl_xor(m0, off));
                m1 = fmaxf(m1, __shfl_xor(m1, off));
            }

            // e = exp(x - M) in place; row sums
            float ps0 = 0.0f, ps1 = 0.0f;
#pragma unroll
            for (int i = 0; i < 8; ++i) {
                x0[i] = exp4m(x0[i], m0);
                x1[i] = exp4m(x1[i], m1);
                ps0 += hsum4(x0[i]);
                ps1 += hsum4(x1[i]);
            }
#pragma unroll
            for (int off = 1; off < 64; off <<= 1) {
                ps0 += __shfl_xor(ps0, off);
                ps1 += __shfl_xor(ps1, off);
            }

            // g = mu/ssum;  u = log(g) - M
            float g0 = mu[b * SS + r0] / ps0;
            float g1 = mu[b * SS + r0 + 1] / ps1;
            if (l == 0) {
                log_u[b * SS + r0]     = __logf(fmaxf(g0, TINYF)) - m0;
                log_u[b * SS + r0 + 1] = __logf(fmaxf(g1, TINYF)) - m1;
            }

            // accumulate column partial into the wave's LDS plane
#pragma unroll
            for (int i = 0; i < 8; ++i) {
                float4 o = acc[w][i * 64 + l];
                o.x = fmaf(g0, x0[i].x, fmaf(g1, x1[i].x, o.x));
                o.y = fmaf(g0, x0[i].y, fmaf(g1, x1[i].y, o.y));
                o.z = fmaf(g0, x0[i].z, fmaf(g1, x1[i].z, o.z));
                o.w = fmaf(g0, x0[i].w, fmaf(g1, x1[i].w, o.w));
                acc[w][i * 64 + l] = o;
            }
        }
        __syncthreads();

        // cross-wave reduce -> device-scope atomic add into S[k] plane
        float* Sk = S + (size_t)k * (BB * TT) + (size_t)b * TT;
#pragma unroll
        for (int j = 0; j < 2; ++j) {
            int g = j * 256 + t;
            float4 s0 = acc[0][g], s1 = acc[1][g], s2 = acc[2][g], s3 = acc[3][g];
            float4 s;
            s.x = (s0.x + s1.x) + (s2.x + s3.x);
            s.y = (s0.y + s1.y) + (s2.y + s3.y);
            s.z = (s0.z + s1.z) + (s2.z + s3.z);
            s.w = (s0.w + s1.w) + (s2.w + s3.w);
            int col = g * 4;
            unsafeAtomicAdd(Sk + col + 0, s.x);
            unsafeAtomicAdd(Sk + col + 1, s.y);
            unsafeAtomicAdd(Sk + col + 2, s.z);
            unsafeAtomicAdd(Sk + col + 3, s.w);
        }
        __syncthreads();                      // all threads' adds complete
        if (t == 0)
            __hip_atomic_fetch_add(&cnt[k], 1, __ATOMIC_RELEASE,
                                   __HIP_MEMORY_SCOPE_AGENT);
    }

    // epilogue: tile==0 blocks compute v_20 and store it for finalize
    if (tile == 0) {
        if (t == 0) {
            while (__hip_atomic_load(&cnt[ITERS - 1], __ATOMIC_ACQUIRE,
                                     __HIP_MEMORY_SCOPE_AGENT) < NBLK)
                __builtin_amdgcn_s_sleep(32);
        }
        __syncthreads();
        const float* Sp = S + (size_t)(ITERS - 1) * (BB * TT) + (size_t)b * TT;
        float4* vf4 = (float4*)(vfinal + (size_t)b * TT);
#pragma unroll
        for (int i = 0; i < 8; ++i) {
            int col = (i * 64 + l) * 4;
            float s0 = aload(Sp + col + 0);
            float s1 = aload(Sp + col + 1);
            float s2 = aload(Sp + col + 2);
            float s3 = aload(Sp + col + 3);
            float4 vn;
            vn.x = ln[i].x + vv[i].x - __logf(fmaxf(s0, TINYF));
            vn.y = ln[i].y + vv[i].y - __logf(fmaxf(s1, TINYF));
            vn.z = ln[i].z + vv[i].z - __logf(fmaxf(s2, TINYF));
            vn.w = ln[i].w + vv[i].w - __logf(fmaxf(s3, TINYF));
            vf4[i * 64 + l] = vn;
        }
    }
}

// transport = exp(log_pi), log_pi = log_u + (-cost/eps) + log_v (fp16 cache)
__global__ __launch_bounds__(256) void finalize(const uint2* __restrict__ c16,
                                                const float* __restrict__ log_u,
                                                const float* __restrict__ log_v,
                                                float* __restrict__ transport,
                                                float* __restrict__ log_pi) {
    int i = blockIdx.x * 256 + threadIdx.x;  // float4 index
    int flat = i * 4;
    int row = flat >> 11;                    // / T
    int t = flat & (TT - 1);
    int b = row >> 11;                       // / S

    float lu = log_u[row];
    float4 lv = *reinterpret_cast<const float4*>(log_v + (size_t)b * TT + t);
    float4 c = unpack4(c16[((size_t)row * TT + t) / 4]);

    float4 lp;
    lp.x = fmaf(NEG_EPS_INV, c.x, lu + lv.x);
    lp.y = fmaf(NEG_EPS_INV, c.y, lu + lv.y);
    lp.z = fmaf(NEG_EPS_INV, c.z, lu + lv.z);
    lp.w = fmaf(NEG_EPS_INV, c.w, lu + lv.w);

    float4 tr;
    tr.x = __expf(lp.x);
    tr.y = __expf(lp.y);
    tr.z = __expf(lp.z);
    tr.w = __expf(lp.w);

    nt_store4(tr, transport + (size_t)row * TT + t);
    nt_store4(lp, log_pi + (size_t)row * TT + t);
}

extern "C" void kernel_launch(void* const* d_in, const int* in_sizes, int n_in,
                              void* d_out, int out_size, void* d_ws, size_t ws_size,
                              hipStream_t stream) {
    const float* cost = (const float*)d_in[0];
    const float* mu = (const float*)d_in[1];
    const float* nu = (const float*)d_in[2];

    float* out = (float*)d_out;
    float* transport = out;
    float* log_pi = out + (size_t)BB * SS * TT;

    // Scratch in d_ws: barrier counters, log_u, vfinal, 20 S planes, fp16 cache.
    float* ws = (float*)d_ws;
    int* cnt = (int*)ws;                      // ITERS ints
    float* log_u = ws + 1024;                 // 16K floats
    float* vfinal = ws + 1024 + 16384;        // 16K floats
    float* S = ws + 65536;                    // ITERS * BB*TT floats = 1.25 MB
    uint2* c16 = (uint2*)(ws + (1 << 23));    // 32 MB offset; 67 MB

    // zero cnt + S (and log_u/vfinal harmlessly) every call -> deterministic
    hipMemsetAsync(ws, 0, (65536 + ITERS * BB * TT) * sizeof(float), stream);

    hipLaunchKernelGGL(sinkhorn_persist, dim3(NTILE, BB), dim3(256), 0, stream,
                       cost, c16, mu, nu, log_u, vfinal, S, cnt);

    hipLaunchKernelGGL(finalize, dim3(BB * SS * TT / 4 / 256), dim3(256), 0, stream,
                       c16, log_u, vfinal, transport, log_pi);
}